// Round 11
// baseline (678.204 us; speedup 1.0000x reference)
//
#include <hip/hip_runtime.h>

#define N_NODES 262144
#define BGRAPHS 1024
#define NPG 256
#define LATENT 256
#define HIDDEN 512
#define BM 128

typedef unsigned short ushort_t;
typedef __attribute__((ext_vector_type(4))) float  f32x4;
typedef __attribute__((ext_vector_type(8))) short  short8;
typedef __attribute__((ext_vector_type(4))) int    int4v;
typedef __attribute__((ext_vector_type(2))) unsigned int uint2v;
typedef __attribute__((ext_vector_type(4))) float  float4v;

__device__ __forceinline__ unsigned int f2bf(float f) {
  union { float f; unsigned int u; } v; v.f = f;
  unsigned int u = v.u;
  return (u + 0x7fffu + ((u >> 16) & 1u)) >> 16;
}
__device__ __forceinline__ unsigned int cvtpk(float lo, float hi) {
  unsigned int r;
  asm("v_cvt_pk_bf16_f32 %0, %1, %2" : "=v"(r) : "v"(lo), "v"(hi));
  return r;
}
__device__ __forceinline__ float silu_f(float x) {
  return x * __builtin_amdgcn_rcpf(1.0f + __expf(-x));
}

// ---------------------------------------------------------------------------
// Weight prep: pre-tile W0/W1 (f32 [K][N]) into per-K-step fragment images:
// byte(kstep,p,n) = kstep*32768 + p*8192 + n*16 (8 bf16: k=kstep*32+p*8..+8,
// col n). W0pre (8 steps) + W1pre (16 steps) contiguous -> 24-step stream.
// ---------------------------------------------------------------------------
__global__ void prep_weights(const float* __restrict__ W0, const float* __restrict__ W1,
                             ushort_t* __restrict__ W0pre, ushort_t* __restrict__ W1pre) {
  int c = blockIdx.x * 256 + threadIdx.x;   // 49152 cells of 8 elems
  const int C0 = 16384;
  const float* src;
  ushort_t* dst;
  int cc;
  if (c < C0) { src = W0; dst = W0pre; cc = c; }
  else        { src = W1; dst = W1pre; cc = c - C0; }
  int kstep = cc >> 11;
  int p = (cc >> 9) & 3;
  int n = cc & 511;
  int kb = kstep * 32 + p * 8;
  unsigned w[4];
#pragma unroll
  for (int j = 0; j < 4; ++j) {
    unsigned lo = f2bf(src[(size_t)(kb + 2 * j) * HIDDEN + n]);
    unsigned hi = f2bf(src[(size_t)(kb + 2 * j + 1) * HIDDEN + n]);
    w[j] = lo | (hi << 16);
  }
  *(int4v*)(dst + (size_t)cc * 8) = *(int4v*)w;
}

// ---------------------------------------------------------------------------
// Fused MLP. BM=128/block, N=512 full. 1024 threads = 16 waves, wave tile
// 32m x 128n: wr = wid&3 (m-quarter), wc = wid>>2 (n-slice of 128).
// acc[8][2] = 64 AGPR; wf[8] = 32 VGPR; arch ~60 -> unified ~124 <= 128 ->
// 4 waves/SIMD (launch_bounds(1024,1): cap = 128 unified, r3/r8/r10-verified
// semantics: cap is unified, residency is unified). W frags: global->VGPR,
// single buffer, refilled after MFMA cluster (4 waves/SIMD hide the L2
// latency cross-wave). LDS: Hc 128 KB = h1 rows [128][1024B]; feat bf16
// parked in high halves during GEMM1 (r8-verified layout).
// ---------------------------------------------------------------------------
__global__ __launch_bounds__(1024, 1) void fused_mlp(
    const float* __restrict__ feat, const ushort_t* __restrict__ W0pre,
    const ushort_t* __restrict__ W1pre, const float* __restrict__ b0,
    const float* __restrict__ b1, const float* __restrict__ W2,
    const float* __restrict__ b2, float* __restrict__ pred) {
  __shared__ __align__(16) char Hc[131072];
  float* Pp = (float*)Hc;

  const int tid = threadIdx.x;
  const int wid = tid >> 6;
  const int lane = tid & 63;
  const int llo = lane & 15;
  const int lhi = lane >> 4;
  const int wr = wid & 3;    // m-quarter: rows wr*32 .. wr*32+31
  const int wc = wid >> 2;   // n-slice: cols wc*128 .. wc*128+127
  const int m0 = blockIdx.x * BM;

  // weight fragment base; step s at +s*32768, frag nt (of 8) at +nt*256
  const char* wp = (const char*)W0pre + lhi * 8192 + (wc * 128 + llo) * 16;
  short8 wf[8];
#pragma unroll
  for (int nt = 0; nt < 8; ++nt) wf[nt] = *(const short8*)(wp + nt * 256);

  // ---- park A: feat rows -> bf16 in Hc high halves (r8 layout) ----
  // row = cch*16 + p*4 + (m>>5), slot = (m&31) ^ (p<<3)
  {
    const int m = tid >> 3, cch = tid & 7;
    const float* ap = feat + (size_t)(m0 + m) * LATENT + cch * 32;
#pragma unroll
    for (int p = 0; p < 4; ++p) {
      float4v x = *(const float4v*)(ap + p * 8);
      float4v y = *(const float4v*)(ap + p * 8 + 4);
      unsigned u[4];
      u[0] = cvtpk(x[0], x[1]);
      u[1] = cvtpk(x[2], x[3]);
      u[2] = cvtpk(y[0], y[1]);
      u[3] = cvtpk(y[2], y[3]);
      *(int4v*)(Hc + ((cch * 16 + p * 4 + (m >> 5)) << 10) + 512 +
                (((m & 31) ^ (p << 3)) << 4)) = *(int4v*)u;
    }
  }
  __syncthreads();

  f32x4 acc[8][2];
#pragma unroll
  for (int nt = 0; nt < 8; ++nt)
#pragma unroll
    for (int mt = 0; mt < 2; ++mt) acc[nt][mt] = 0.0f;

  // ================= GEMM1: 8 K-steps =================
  {
    // A frag: row = s*16 + lhi*4 + wr; slot = (mt*16+llo) ^ (lhi<<3)
    const char* abp = Hc + 512 + ((lhi * 4 + wr) << 10);
    const int off = (llo ^ (lhi << 3)) << 4;
    const char* wpp = wp;
#pragma unroll 1
    for (int s = 0; s < 8; ++s) {
      short8 xf0 = *(const short8*)(abp + off);
      short8 xf1 = *(const short8*)(abp + (off ^ 256));
      __builtin_amdgcn_s_setprio(1);
#pragma unroll
      for (int nt = 0; nt < 8; ++nt) {
        acc[nt][0] = __builtin_amdgcn_mfma_f32_16x16x32_bf16(wf[nt], xf0, acc[nt][0], 0, 0, 0);
        acc[nt][1] = __builtin_amdgcn_mfma_f32_16x16x32_bf16(wf[nt], xf1, acc[nt][1], 0, 0, 0);
      }
      __builtin_amdgcn_s_setprio(0);
#pragma unroll
      for (int nt = 0; nt < 8; ++nt) wf[nt] = *(const short8*)(wpp + 32768 + nt * 256);
      wpp += 32768;
      abp += 16384;
    }
  }

  // ---- epilogue 1: h1 = silu(acc + b0) -> Hc rows (swizzled) ----
  __syncthreads();  // all park reads done
#pragma unroll
  for (int nt = 0; nt < 8; ++nt) {
    int nb = wc * 128 + nt * 16 + lhi * 4;
    float4v bv = *(const float4v*)(b0 + nb);
#pragma unroll
    for (int mt = 0; mt < 2; ++mt) {
      int m = wr * 32 + mt * 16 + llo;
      float s0 = silu_f(acc[nt][mt][0] + bv[0]);
      float s1 = silu_f(acc[nt][mt][1] + bv[1]);
      float s2 = silu_f(acc[nt][mt][2] + bv[2]);
      float s3 = silu_f(acc[nt][mt][3] + bv[3]);
      uint2v pk;
      pk.x = cvtpk(s0, s1);
      pk.y = cvtpk(s2, s3);
      *(uint2v*)(Hc + m * 1024 + ((nb * 2) ^ (llo << 4))) = pk;
    }
  }
#pragma unroll
  for (int nt = 0; nt < 8; ++nt)
#pragma unroll
    for (int mt = 0; mt < 2; ++mt) acc[nt][mt] = 0.0f;
  __syncthreads();  // h1 visible to all waves

  // ================= GEMM2: 16 K-steps =================
  {
    const char* hrow = Hc + ((wr * 32 + llo) << 10);
    const char* wpp = wp + 8 * 32768;
#pragma unroll 1
    for (int t = 0; t < 16; ++t) {
      const int col = ((t * 64 + lhi * 16) ^ (llo << 4));
      short8 xf0 = *(const short8*)(hrow + col);
      short8 xf1 = *(const short8*)(hrow + 16384 + col);
      __builtin_amdgcn_s_setprio(1);
#pragma unroll
      for (int nt = 0; nt < 8; ++nt) {
        acc[nt][0] = __builtin_amdgcn_mfma_f32_16x16x32_bf16(wf[nt], xf0, acc[nt][0], 0, 0, 0);
        acc[nt][1] = __builtin_amdgcn_mfma_f32_16x16x32_bf16(wf[nt], xf1, acc[nt][1], 0, 0, 0);
      }
      __builtin_amdgcn_s_setprio(0);
      if (t < 15) {
#pragma unroll
        for (int nt = 0; nt < 8; ++nt) wf[nt] = *(const short8*)(wpp + 32768 + nt * 256);
        wpp += 32768;
      }
    }
  }

  // ---- epilogue 2: pacc = silu(acc + b1) @ W2 (registers only) ----
  float pacc[2][3];
#pragma unroll
  for (int mt = 0; mt < 2; ++mt) { pacc[mt][0] = 0.f; pacc[mt][1] = 0.f; pacc[mt][2] = 0.f; }
#pragma unroll
  for (int nt = 0; nt < 8; ++nt) {
    int nb = wc * 128 + nt * 16 + lhi * 4;
    float4v bv = *(const float4v*)(b1 + nb);
#pragma unroll
    for (int r = 0; r < 4; ++r) {
      float w20 = W2[(nb + r) * 3 + 0];
      float w21 = W2[(nb + r) * 3 + 1];
      float w22 = W2[(nb + r) * 3 + 2];
#pragma unroll
      for (int mt = 0; mt < 2; ++mt) {
        float h = silu_f(acc[nt][mt][r] + bv[r]);
        pacc[mt][0] += h * w20; pacc[mt][1] += h * w21; pacc[mt][2] += h * w22;
      }
    }
  }
  __syncthreads();  // all h1 reads done before Pp overlays Hc
#pragma unroll
  for (int mt = 0; mt < 2; ++mt)
#pragma unroll
    for (int o = 0; o < 3; ++o) {
      float v = pacc[mt][o];
      v += __shfl_xor(v, 16);
      v += __shfl_xor(v, 32);
      if (lane < 16) Pp[wid * 96 + (mt * 16 + llo) * 3 + o] = v;
    }
  __syncthreads();
  if (tid < 384) {
    int m = tid / 3, o = tid - m * 3;
    float v = b2[o];
#pragma unroll
    for (int w4 = 0; w4 < 4; ++w4) v += Pp[(w4 * 4 + (m >> 5)) * 96 + (m & 31) * 3 + o];
    pred[(size_t)(m0 + m) * 3 + o] = v;
  }
}

// ---------------------------------------------------------------------------
// Per-graph finalize: mean removal + analytic torque removal. 1 block/graph.
// ---------------------------------------------------------------------------
template<int NV>
__device__ __forceinline__ void block_reduce(const float* v, float (*sc)[16], int wid, int lane,
                                             float* tot) {
#pragma unroll
  for (int j = 0; j < NV; ++j) {
    float x = v[j];
#pragma unroll
    for (int off = 32; off >= 1; off >>= 1) x += __shfl_down(x, off);
    if (lane == 0) sc[wid][j] = x;
  }
  __syncthreads();
#pragma unroll
  for (int j = 0; j < NV; ++j) tot[j] = sc[0][j] + sc[1][j] + sc[2][j] + sc[3][j];
  __syncthreads();
}

__global__ __launch_bounds__(256) void finalize_kernel(
    const float* __restrict__ pred, const float* __restrict__ pos,
    const float* __restrict__ cell, const int* __restrict__ n_node,
    float* __restrict__ out) {
  __shared__ float sc[4][16];
  int g = blockIdx.x, tid = threadIdx.x;
  int wid = tid >> 6, lane = tid & 63;
  size_t i = (size_t)g * NPG + tid;

  float p0 = pred[i * 3 + 0], p1 = pred[i * 3 + 1], p2 = pred[i * 3 + 2];
  float q0 = pos[i * 3 + 0], q1 = pos[i * 3 + 1], q2 = pos[i * 3 + 2];

  float v1[6] = {p0, p1, p2, q0, q1, q2};
  float t1[6];
  block_reduce<6>(v1, sc, wid, lane, t1);

  float cnt = (float)n_node[g];
  float pc0 = p0 - t1[0] / cnt, pc1 = p1 - t1[1] / cnt, pc2 = p2 - t1[2] / cnt;
  float r0 = q0 - t1[3] / cnt, r1 = q1 - t1[4] / cnt, r2 = q2 - t1[5] / cnt;

  float v2[10] = {r1 * pc2 - r2 * pc1, r2 * pc0 - r0 * pc2, r0 * pc1 - r1 * pc0,
                  r0 * r0 + r1 * r1 + r2 * r2,
                  r0 * r0, r0 * r1, r0 * r2, r1 * r1, r1 * r2, r2 * r2};
  float t2[10];
  block_reduce<10>(v2, sc, wid, lane, t2);

  double s = (double)t2[3];
  double a = (double)t2[4] - s, b = (double)t2[5], c = (double)t2[6];
  double d = (double)t2[7] - s, e = (double)t2[8], f = (double)t2[9] - s;
  double A00 = d * f - e * e;
  double A01 = c * e - b * f;
  double A02 = b * e - c * d;
  double A11 = a * f - c * c;
  double A12 = b * c - a * e;
  double A22 = a * d - b * b;
  double det = a * A00 + b * A01 + c * A02;
  double rinv = 1.0 / det;
  double rhs0 = -(double)t2[0], rhs1 = -(double)t2[1], rhs2 = -(double)t2[2];
  double mu0 = (A00 * rhs0 + A01 * rhs1 + A02 * rhs2) * rinv;
  double mu1 = (A01 * rhs0 + A11 * rhs1 + A12 * rhs2) * rinv;
  double mu2 = (A02 * rhs0 + A12 * rhs1 + A22 * rhs2) * rinv;

  bool nopbc = true;
#pragma unroll
  for (int j = 0; j < 9; ++j) nopbc = nopbc && (cell[g * 9 + j] == 0.0f);

  float d0 = (float)((double)r1 * mu2 - (double)r2 * mu1);
  float d1 = (float)((double)r2 * mu0 - (double)r0 * mu2);
  float d2 = (float)((double)r0 * mu1 - (double)r1 * mu0);

  out[i * 3 + 0] = pc0 + (nopbc ? d0 : 0.0f);
  out[i * 3 + 1] = pc1 + (nopbc ? d1 : 0.0f);
  out[i * 3 + 2] = pc2 + (nopbc ? d2 : 0.0f);
}

// ---------------------------------------------------------------------------
extern "C" void kernel_launch(void* const* d_in, const int* in_sizes, int n_in,
                              void* d_out, int out_size, void* d_ws, size_t ws_size,
                              hipStream_t stream) {
  const float* feat = (const float*)d_in[0];
  const float* positions = (const float*)d_in[1];
  const float* cell = (const float*)d_in[2];
  const int* n_node = (const int*)d_in[3];
  const float* W0 = (const float*)d_in[4];
  const float* b0 = (const float*)d_in[5];
  const float* W1 = (const float*)d_in[6];
  const float* b1 = (const float*)d_in[7];
  const float* W2 = (const float*)d_in[8];
  const float* b2 = (const float*)d_in[9];
  float* out = (float*)d_out;

  char* ws = (char*)d_ws;
  ushort_t* W0pre = (ushort_t*)ws;                       // 256 KB (8 steps)
  ushort_t* W1pre = (ushort_t*)(ws + 262144);            // 512 KB (16 steps, contiguous)
  float* pred = (float*)(ws + 786432);                   // 3 MB

  hipLaunchKernelGGL(prep_weights, dim3(192), dim3(256), 0, stream, W0, W1, W0pre, W1pre);
  hipLaunchKernelGGL(fused_mlp, dim3(N_NODES / BM), dim3(1024), 0, stream,
                     feat, W0pre, W1pre, b0, b1, W2, b2, pred);
  hipLaunchKernelGGL(finalize_kernel, dim3(BGRAPHS), dim3(256), 0, stream, pred, positions, cell,
                     n_node, out);
}

// Round 12
// 422.247 us; speedup vs baseline: 1.6062x; 1.6062x over previous
//
#include <hip/hip_runtime.h>

#define N_NODES 262144
#define BGRAPHS 1024
#define NPG 256
#define LATENT 256
#define HIDDEN 512
#define BM 128

typedef unsigned short ushort_t;
typedef __attribute__((ext_vector_type(4))) float  f32x4;
typedef __attribute__((ext_vector_type(8))) short  short8;
typedef __attribute__((ext_vector_type(4))) int    int4v;
typedef __attribute__((ext_vector_type(2))) unsigned int uint2v;
typedef __attribute__((ext_vector_type(4))) float  float4v;

__device__ __forceinline__ unsigned int f2bf(float f) {
  union { float f; unsigned int u; } v; v.f = f;
  unsigned int u = v.u;
  return (u + 0x7fffu + ((u >> 16) & 1u)) >> 16;
}
__device__ __forceinline__ unsigned int cvtpk(float lo, float hi) {
  unsigned int r;
  asm("v_cvt_pk_bf16_f32 %0, %1, %2" : "=v"(r) : "v"(lo), "v"(hi));
  return r;
}
__device__ __forceinline__ float silu_f(float x) {
  return x * __builtin_amdgcn_rcpf(1.0f + __expf(-x));
}

// ---------------------------------------------------------------------------
// Weight prep: pre-tile W0/W1 (f32 [K][N]) into per-K-step fragment images:
// byte(kstep,p,n) = kstep*32768 + p*8192 + n*16 (8 bf16: k=kstep*32+p*8..+8,
// col n). W0pre (8 steps) + W1pre (16 steps) contiguous -> 24-step stream.
// ---------------------------------------------------------------------------
__global__ void prep_weights(const float* __restrict__ W0, const float* __restrict__ W1,
                             ushort_t* __restrict__ W0pre, ushort_t* __restrict__ W1pre) {
  int c = blockIdx.x * 256 + threadIdx.x;   // 49152 cells of 8 elems
  const int C0 = 16384;
  const float* src;
  ushort_t* dst;
  int cc;
  if (c < C0) { src = W0; dst = W0pre; cc = c; }
  else        { src = W1; dst = W1pre; cc = c - C0; }
  int kstep = cc >> 11;
  int p = (cc >> 9) & 3;
  int n = cc & 511;
  int kb = kstep * 32 + p * 8;
  unsigned w[4];
#pragma unroll
  for (int j = 0; j < 4; ++j) {
    unsigned lo = f2bf(src[(size_t)(kb + 2 * j) * HIDDEN + n]);
    unsigned hi = f2bf(src[(size_t)(kb + 2 * j + 1) * HIDDEN + n]);
    w[j] = lo | (hi << 16);
  }
  *(int4v*)(dst + (size_t)cc * 8) = *(int4v*)w;
}

// ---------------------------------------------------------------------------
// Fused MLP. BM=128/block, N=512 full. 1024 threads = 16 waves, wave tile
// 64m x 64n (wr=wid&1 m-half, wc=wid>>1 n-slice), acc[4][4] = 64 AGPR.
// __launch_bounds__(1024,1): single 16-wave block FORCES 4 waves/SIMD ->
// unified cap 128 enforced on arch+AGPR [r8/r11-verified]. Arch dieted to
// ~50 (wf[4]=16, xf streamed, wf freed across epilogue1) so nothing spills.
// W frags: global->VGPR, refilled after MFMA cluster. LDS: Hc 128 KB =
// h1 rows [128][1024B]; feat bf16 parked in high halves during GEMM1
// (r8-verified layout: row = cch*16+p*4+(m>>5), slot = (m&31)^(p<<3)).
// ---------------------------------------------------------------------------
__global__ __launch_bounds__(1024, 1) void fused_mlp(
    const float* __restrict__ feat, const ushort_t* __restrict__ W0pre,
    const ushort_t* __restrict__ W1pre, const float* __restrict__ b0,
    const float* __restrict__ b1, const float* __restrict__ W2,
    const float* __restrict__ b2, float* __restrict__ pred) {
  __shared__ __align__(16) char Hc[131072];
  float* Pp = (float*)Hc;

  const int tid = threadIdx.x;
  const int wid = tid >> 6;
  const int lane = tid & 63;
  const int llo = lane & 15;
  const int lhi = lane >> 4;
  const int wr = wid & 1;    // m-half: rows wr*64 .. wr*64+63
  const int wc = wid >> 1;   // n-slice: cols wc*64 .. wc*64+63
  const int m0 = blockIdx.x * BM;

  // weight fragment base; step s at +s*32768, frag nt at +nt*256
  const char* wp = (const char*)W0pre + lhi * 8192 + (wc * 64 + llo) * 16;
  short8 wf[4];
#pragma unroll
  for (int nt = 0; nt < 4; ++nt) wf[nt] = *(const short8*)(wp + nt * 256);

  // ---- park A: feat rows -> bf16 in Hc high halves ----
  {
    const int m = tid >> 3, cch = tid & 7;
    const float* ap = feat + (size_t)(m0 + m) * LATENT + cch * 32;
#pragma unroll
    for (int p = 0; p < 4; ++p) {
      float4v x = *(const float4v*)(ap + p * 8);
      float4v y = *(const float4v*)(ap + p * 8 + 4);
      unsigned u[4];
      u[0] = cvtpk(x[0], x[1]);
      u[1] = cvtpk(x[2], x[3]);
      u[2] = cvtpk(y[0], y[1]);
      u[3] = cvtpk(y[2], y[3]);
      *(int4v*)(Hc + ((cch * 16 + p * 4 + (m >> 5)) << 10) + 512 +
                (((m & 31) ^ (p << 3)) << 4)) = *(int4v*)u;
    }
  }
  __syncthreads();

  f32x4 acc[4][4];
#pragma unroll
  for (int nt = 0; nt < 4; ++nt)
#pragma unroll
    for (int mt = 0; mt < 4; ++mt) acc[nt][mt] = 0.0f;

  // ================= GEMM1: 8 K-steps =================
  {
    // A frag row = s*16 + lhi*4 + wr*2 + (mt>>1); slot ((mt&1)*16+llo)^(lhi<<3)
    const char* abp = Hc + 512 + ((lhi * 4 + wr * 2) << 10);
    const int xe = ((llo ^ (lhi << 3)) << 4);
    const int xo = (((16 + llo) ^ (lhi << 3)) << 4);  // == xe ^ 256
    const char* wpp = wp;
#pragma unroll 1
    for (int s = 0; s < 8; ++s) {
      __builtin_amdgcn_s_setprio(1);
#pragma unroll
      for (int mt = 0; mt < 4; ++mt) {
        short8 xf = *(const short8*)(abp + ((mt >> 1) << 10) + ((mt & 1) ? xo : xe));
#pragma unroll
        for (int nt = 0; nt < 4; ++nt)
          acc[nt][mt] = __builtin_amdgcn_mfma_f32_16x16x32_bf16(wf[nt], xf, acc[nt][mt], 0, 0, 0);
      }
      __builtin_amdgcn_s_setprio(0);
      if (s < 7) {
#pragma unroll
        for (int nt = 0; nt < 4; ++nt) wf[nt] = *(const short8*)(wpp + 32768 + nt * 256);
        wpp += 32768;
      }
      abp += 16384;
    }
  }

  // ---- epilogue 1: h1 = silu(acc + b0) -> Hc rows (swizzled); wf dead here ----
  __syncthreads();  // all park reads done
#pragma unroll
  for (int nt = 0; nt < 4; ++nt) {
    int nb = wc * 64 + nt * 16 + lhi * 4;
    float4v bv = *(const float4v*)(b0 + nb);
#pragma unroll
    for (int mt = 0; mt < 4; ++mt) {
      int m = wr * 64 + mt * 16 + llo;
      float s0 = silu_f(acc[nt][mt][0] + bv[0]);
      float s1 = silu_f(acc[nt][mt][1] + bv[1]);
      float s2 = silu_f(acc[nt][mt][2] + bv[2]);
      float s3 = silu_f(acc[nt][mt][3] + bv[3]);
      uint2v pk;
      pk.x = cvtpk(s0, s1);
      pk.y = cvtpk(s2, s3);
      *(uint2v*)(Hc + m * 1024 + ((nb * 2) ^ (llo << 4))) = pk;
    }
  }
#pragma unroll
  for (int nt = 0; nt < 4; ++nt)
#pragma unroll
    for (int mt = 0; mt < 4; ++mt) acc[nt][mt] = 0.0f;
  __syncthreads();  // h1 visible to all waves

  // ================= GEMM2: 16 K-steps =================
  {
    const char* hrow = Hc + ((wr * 64 + llo) << 10);
    const char* wpp = wp + 8 * 32768;
    // wf for GEMM2 step 0 (freed across epilogue1; one L2 latency per block)
#pragma unroll
    for (int nt = 0; nt < 4; ++nt) wf[nt] = *(const short8*)(wpp + nt * 256);
#pragma unroll 1
    for (int t = 0; t < 16; ++t) {
      const int col = ((t * 64 + lhi * 16) ^ (llo << 4));
      __builtin_amdgcn_s_setprio(1);
#pragma unroll
      for (int mt = 0; mt < 4; ++mt) {
        short8 xf = *(const short8*)(hrow + mt * 16384 + col);
#pragma unroll
        for (int nt = 0; nt < 4; ++nt)
          acc[nt][mt] = __builtin_amdgcn_mfma_f32_16x16x32_bf16(wf[nt], xf, acc[nt][mt], 0, 0, 0);
      }
      __builtin_amdgcn_s_setprio(0);
      if (t < 15) {
#pragma unroll
        for (int nt = 0; nt < 4; ++nt) wf[nt] = *(const short8*)(wpp + 32768 + nt * 256);
        wpp += 32768;
      }
    }
  }

  // ---- epilogue 2: pacc = silu(acc + b1) @ W2 (registers only) ----
  float pacc[4][3];
#pragma unroll
  for (int mt = 0; mt < 4; ++mt) { pacc[mt][0] = 0.f; pacc[mt][1] = 0.f; pacc[mt][2] = 0.f; }
#pragma unroll
  for (int nt = 0; nt < 4; ++nt) {
    int nb = wc * 64 + nt * 16 + lhi * 4;
    float4v bv = *(const float4v*)(b1 + nb);
#pragma unroll
    for (int r = 0; r < 4; ++r) {
      float w20 = W2[(nb + r) * 3 + 0];
      float w21 = W2[(nb + r) * 3 + 1];
      float w22 = W2[(nb + r) * 3 + 2];
#pragma unroll
      for (int mt = 0; mt < 4; ++mt) {
        float h = silu_f(acc[nt][mt][r] + bv[r]);
        pacc[mt][0] += h * w20; pacc[mt][1] += h * w21; pacc[mt][2] += h * w22;
      }
    }
  }
  __syncthreads();  // all h1 reads done before Pp overlays Hc
#pragma unroll
  for (int mt = 0; mt < 4; ++mt)
#pragma unroll
    for (int o = 0; o < 3; ++o) {
      float v = pacc[mt][o];
      v += __shfl_xor(v, 16);
      v += __shfl_xor(v, 32);
      if (lane < 16) Pp[wid * 192 + (mt * 16 + llo) * 3 + o] = v;
    }
  __syncthreads();
  if (tid < 384) {
    int m = tid / 3, o = tid - m * 3;
    int wrr = m >> 6, ml = m & 63;
    float v = b2[o];
#pragma unroll
    for (int ww = 0; ww < 8; ++ww) v += Pp[(2 * ww + wrr) * 192 + ml * 3 + o];
    pred[(size_t)(m0 + m) * 3 + o] = v;
  }
}

// ---------------------------------------------------------------------------
// Per-graph finalize: mean removal + analytic torque removal. 1 block/graph.
// ---------------------------------------------------------------------------
template<int NV>
__device__ __forceinline__ void block_reduce(const float* v, float (*sc)[16], int wid, int lane,
                                             float* tot) {
#pragma unroll
  for (int j = 0; j < NV; ++j) {
    float x = v[j];
#pragma unroll
    for (int off = 32; off >= 1; off >>= 1) x += __shfl_down(x, off);
    if (lane == 0) sc[wid][j] = x;
  }
  __syncthreads();
#pragma unroll
  for (int j = 0; j < NV; ++j) tot[j] = sc[0][j] + sc[1][j] + sc[2][j] + sc[3][j];
  __syncthreads();
}

__global__ __launch_bounds__(256) void finalize_kernel(
    const float* __restrict__ pred, const float* __restrict__ pos,
    const float* __restrict__ cell, const int* __restrict__ n_node,
    float* __restrict__ out) {
  __shared__ float sc[4][16];
  int g = blockIdx.x, tid = threadIdx.x;
  int wid = tid >> 6, lane = tid & 63;
  size_t i = (size_t)g * NPG + tid;

  float p0 = pred[i * 3 + 0], p1 = pred[i * 3 + 1], p2 = pred[i * 3 + 2];
  float q0 = pos[i * 3 + 0], q1 = pos[i * 3 + 1], q2 = pos[i * 3 + 2];

  float v1[6] = {p0, p1, p2, q0, q1, q2};
  float t1[6];
  block_reduce<6>(v1, sc, wid, lane, t1);

  float cnt = (float)n_node[g];
  float pc0 = p0 - t1[0] / cnt, pc1 = p1 - t1[1] / cnt, pc2 = p2 - t1[2] / cnt;
  float r0 = q0 - t1[3] / cnt, r1 = q1 - t1[4] / cnt, r2 = q2 - t1[5] / cnt;

  float v2[10] = {r1 * pc2 - r2 * pc1, r2 * pc0 - r0 * pc2, r0 * pc1 - r1 * pc0,
                  r0 * r0 + r1 * r1 + r2 * r2,
                  r0 * r0, r0 * r1, r0 * r2, r1 * r1, r1 * r2, r2 * r2};
  float t2[10];
  block_reduce<10>(v2, sc, wid, lane, t2);

  double s = (double)t2[3];
  double a = (double)t2[4] - s, b = (double)t2[5], c = (double)t2[6];
  double d = (double)t2[7] - s, e = (double)t2[8], f = (double)t2[9] - s;
  double A00 = d * f - e * e;
  double A01 = c * e - b * f;
  double A02 = b * e - c * d;
  double A11 = a * f - c * c;
  double A12 = b * c - a * e;
  double A22 = a * d - b * b;
  double det = a * A00 + b * A01 + c * A02;
  double rinv = 1.0 / det;
  double rhs0 = -(double)t2[0], rhs1 = -(double)t2[1], rhs2 = -(double)t2[2];
  double mu0 = (A00 * rhs0 + A01 * rhs1 + A02 * rhs2) * rinv;
  double mu1 = (A01 * rhs0 + A11 * rhs1 + A12 * rhs2) * rinv;
  double mu2 = (A02 * rhs0 + A12 * rhs1 + A22 * rhs2) * rinv;

  bool nopbc = true;
#pragma unroll
  for (int j = 0; j < 9; ++j) nopbc = nopbc && (cell[g * 9 + j] == 0.0f);

  float d0 = (float)((double)r1 * mu2 - (double)r2 * mu1);
  float d1 = (float)((double)r2 * mu0 - (double)r0 * mu2);
  float d2 = (float)((double)r0 * mu1 - (double)r1 * mu0);

  out[i * 3 + 0] = pc0 + (nopbc ? d0 : 0.0f);
  out[i * 3 + 1] = pc1 + (nopbc ? d1 : 0.0f);
  out[i * 3 + 2] = pc2 + (nopbc ? d2 : 0.0f);
}

// ---------------------------------------------------------------------------
extern "C" void kernel_launch(void* const* d_in, const int* in_sizes, int n_in,
                              void* d_out, int out_size, void* d_ws, size_t ws_size,
                              hipStream_t stream) {
  const float* feat = (const float*)d_in[0];
  const float* positions = (const float*)d_in[1];
  const float* cell = (const float*)d_in[2];
  const int* n_node = (const int*)d_in[3];
  const float* W0 = (const float*)d_in[4];
  const float* b0 = (const float*)d_in[5];
  const float* W1 = (const float*)d_in[6];
  const float* b1 = (const float*)d_in[7];
  const float* W2 = (const float*)d_in[8];
  const float* b2 = (const float*)d_in[9];
  float* out = (float*)d_out;

  char* ws = (char*)d_ws;
  ushort_t* W0pre = (ushort_t*)ws;                       // 256 KB (8 steps)
  ushort_t* W1pre = (ushort_t*)(ws + 262144);            // 512 KB (16 steps, contiguous)
  float* pred = (float*)(ws + 786432);                   // 3 MB

  hipLaunchKernelGGL(prep_weights, dim3(192), dim3(256), 0, stream, W0, W1, W0pre, W1pre);
  hipLaunchKernelGGL(fused_mlp, dim3(N_NODES / BM), dim3(1024), 0, stream,
                     feat, W0pre, W1pre, b0, b1, W2, b2, pred);
  hipLaunchKernelGGL(finalize_kernel, dim3(BGRAPHS), dim3(256), 0, stream, pred, positions, cell,
                     n_node, out);
}

// Round 13
// 280.609 us; speedup vs baseline: 2.4169x; 1.5048x over previous
//
#include <hip/hip_runtime.h>

#define N_NODES 262144
#define BGRAPHS 1024
#define NPG 256
#define LATENT 256
#define HIDDEN 512
#define BM 64

typedef unsigned short ushort_t;
typedef __attribute__((ext_vector_type(4))) float  f32x4;
typedef __attribute__((ext_vector_type(8))) short  short8;
typedef __attribute__((ext_vector_type(4))) int    int4v;
typedef __attribute__((ext_vector_type(2))) unsigned int uint2v;
typedef __attribute__((ext_vector_type(4))) float  float4v;

__device__ __forceinline__ unsigned int f2bf(float f) {
  union { float f; unsigned int u; } v; v.f = f;
  unsigned int u = v.u;
  return (u + 0x7fffu + ((u >> 16) & 1u)) >> 16;
}
__device__ __forceinline__ unsigned int cvtpk(float lo, float hi) {
  unsigned int r;
  asm("v_cvt_pk_bf16_f32 %0, %1, %2" : "=v"(r) : "v"(lo), "v"(hi));
  return r;
}
__device__ __forceinline__ float silu_f(float x) {
  return x * __builtin_amdgcn_rcpf(1.0f + __expf(-x));
}

// ---------------------------------------------------------------------------
// Weight prep: pre-tile W0/W1 (f32 [K][N]) into per-K-step fragment images:
// byte(kstep,p,n) = kstep*32768 + p*8192 + n*16 (8 bf16: k=kstep*32+p*8..+8,
// col n). W0pre (8 steps) + W1pre (16 steps) contiguous -> 24-step stream.
// ---------------------------------------------------------------------------
__global__ void prep_weights(const float* __restrict__ W0, const float* __restrict__ W1,
                             ushort_t* __restrict__ W0pre, ushort_t* __restrict__ W1pre) {
  int c = blockIdx.x * 256 + threadIdx.x;   // 49152 cells of 8 elems
  const int C0 = 16384;
  const float* src;
  ushort_t* dst;
  int cc;
  if (c < C0) { src = W0; dst = W0pre; cc = c; }
  else        { src = W1; dst = W1pre; cc = c - C0; }
  int kstep = cc >> 11;
  int p = (cc >> 9) & 3;
  int n = cc & 511;
  int kb = kstep * 32 + p * 8;
  unsigned w[4];
#pragma unroll
  for (int j = 0; j < 4; ++j) {
    unsigned lo = f2bf(src[(size_t)(kb + 2 * j) * HIDDEN + n]);
    unsigned hi = f2bf(src[(size_t)(kb + 2 * j + 1) * HIDDEN + n]);
    w[j] = lo | (hi << 16);
  }
  *(int4v*)(dst + (size_t)cc * 8) = *(int4v*)w;
}

// ---------------------------------------------------------------------------
// Fused MLP. BM=64/block, N=512 full. 1024 threads = 16 waves, wave tile
// 64m x 32n (wc = wid, covers n = wid*32..wid*32+31; every wave spans all
// 64 m rows). acc[2][4] = 32 AGPR; wf[2] = 8 VGPR; xf streamed -> arch
// ~55-65 <= 96 cap (16-wave block forces 4 waves/SIMD -> unified <= 128
// enforced; arch cap = 128 - 32 AGPR = 96 [r8/r11/r12-verified semantics]).
// No W duplication: each wave owns a distinct 32-wide n-slice.
// LDS: Hc 64 KB = h1 rows [64][1024B]; feat bf16 parked in high halves
// during GEMM1 (r9-verified layout: row = cch*8+p*2+(m>>5),
// slot = (m&31)^(cch<<2)^(p<<1)). W frags: global->VGPR, refill after MFMA.
// ---------------------------------------------------------------------------
__global__ __launch_bounds__(1024, 1) void fused_mlp(
    const float* __restrict__ feat, const ushort_t* __restrict__ W0pre,
    const ushort_t* __restrict__ W1pre, const float* __restrict__ b0,
    const float* __restrict__ b1, const float* __restrict__ W2,
    const float* __restrict__ b2, float* __restrict__ pred) {
  __shared__ __align__(16) char Hc[65536];
  float* Pp = (float*)Hc;

  const int tid = threadIdx.x;
  const int wid = tid >> 6;    // n-slice: cols wid*32 .. wid*32+31
  const int lane = tid & 63;
  const int llo = lane & 15;
  const int lhi = lane >> 4;
  const int m0 = blockIdx.x * BM;

  // weight fragment base; step s at +s*32768, frag nt (0..1) at +nt*256
  const char* wp = (const char*)W0pre + lhi * 8192 + (wid * 32 + llo) * 16;
  short8 wf[2];
#pragma unroll
  for (int nt = 0; nt < 2; ++nt) wf[nt] = *(const short8*)(wp + nt * 256);

  // ---- park A: feat rows -> bf16 in Hc high halves (r9 layout) ----
  {
    const int m = tid >> 4, q = tid & 15;
    const int cch = q >> 1, p0q = (q & 1) * 2;
    const float* ap = feat + (size_t)(m0 + m) * LATENT + cch * 32 + p0q * 8;
#pragma unroll
    for (int j = 0; j < 2; ++j) {
      const int p = p0q + j;
      float4v x = *(const float4v*)(ap + j * 8);
      float4v y = *(const float4v*)(ap + j * 8 + 4);
      unsigned u[4];
      u[0] = cvtpk(x[0], x[1]);
      u[1] = cvtpk(x[2], x[3]);
      u[2] = cvtpk(y[0], y[1]);
      u[3] = cvtpk(y[2], y[3]);
      int row = cch * 8 + p * 2 + (m >> 5);
      int slot = (m & 31) ^ (cch << 2) ^ (p << 1);
      *(int4v*)(Hc + row * 1024 + 512 + slot * 16) = *(int4v*)u;
    }
  }
  __syncthreads();

  f32x4 acc[2][4];
#pragma unroll
  for (int nt = 0; nt < 2; ++nt)
#pragma unroll
    for (int mt = 0; mt < 4; ++mt) acc[nt][mt] = 0.0f;

  // ================= GEMM1: 8 K-steps =================
  {
    const int pre = llo ^ (lhi << 1);   // no bit 4
    const char* wpp = wp;
#pragma unroll 1
    for (int s = 0; s < 8; ++s) {
      const char* abase = Hc + 512 + s * 8192 + lhi * 2048;
      const int off_e = (pre ^ (s << 2)) << 4;
      __builtin_amdgcn_s_setprio(1);
#pragma unroll
      for (int mt = 0; mt < 4; ++mt) {
        short8 xf = *(const short8*)(abase + ((mt >> 1) << 10) +
                                     ((mt & 1) ? (off_e ^ 256) : off_e));
#pragma unroll
        for (int nt = 0; nt < 2; ++nt)
          acc[nt][mt] = __builtin_amdgcn_mfma_f32_16x16x32_bf16(wf[nt], xf, acc[nt][mt], 0, 0, 0);
      }
      __builtin_amdgcn_s_setprio(0);
#pragma unroll
      for (int nt = 0; nt < 2; ++nt) wf[nt] = *(const short8*)(wpp + 32768 + nt * 256);
      wpp += 32768;
    }
  }

  // ---- epilogue 1: h1 = silu(acc + b0) -> Hc rows (swizzled) ----
  __syncthreads();  // all park reads done
#pragma unroll
  for (int nt = 0; nt < 2; ++nt) {
    int nb = wid * 32 + nt * 16 + lhi * 4;
    float4v bv = *(const float4v*)(b0 + nb);
#pragma unroll
    for (int mt = 0; mt < 4; ++mt) {
      int m = mt * 16 + llo;
      float s0 = silu_f(acc[nt][mt][0] + bv[0]);
      float s1 = silu_f(acc[nt][mt][1] + bv[1]);
      float s2 = silu_f(acc[nt][mt][2] + bv[2]);
      float s3 = silu_f(acc[nt][mt][3] + bv[3]);
      uint2v pk;
      pk.x = cvtpk(s0, s1);
      pk.y = cvtpk(s2, s3);
      *(uint2v*)(Hc + m * 1024 + ((nb * 2) ^ (llo << 4))) = pk;
    }
  }
#pragma unroll
  for (int nt = 0; nt < 2; ++nt)
#pragma unroll
    for (int mt = 0; mt < 4; ++mt) acc[nt][mt] = 0.0f;
  __syncthreads();  // h1 visible to all waves

  // ================= GEMM2: 16 K-steps =================
  {
    const char* hrow = Hc + llo * 1024;
    const char* wpp = wp + 8 * 32768;
#pragma unroll 1
    for (int t = 0; t < 16; ++t) {
      const int col = ((t * 64 + lhi * 16) ^ (llo << 4));
      __builtin_amdgcn_s_setprio(1);
#pragma unroll
      for (int mt = 0; mt < 4; ++mt) {
        short8 xf = *(const short8*)(hrow + mt * 16384 + col);
#pragma unroll
        for (int nt = 0; nt < 2; ++nt)
          acc[nt][mt] = __builtin_amdgcn_mfma_f32_16x16x32_bf16(wf[nt], xf, acc[nt][mt], 0, 0, 0);
      }
      __builtin_amdgcn_s_setprio(0);
      if (t < 15) {
#pragma unroll
        for (int nt = 0; nt < 2; ++nt) wf[nt] = *(const short8*)(wpp + 32768 + nt * 256);
        wpp += 32768;
      }
    }
  }

  // ---- epilogue 2: pacc = silu(acc + b1) @ W2 (registers only) ----
  float pacc[4][3];
#pragma unroll
  for (int mt = 0; mt < 4; ++mt) { pacc[mt][0] = 0.f; pacc[mt][1] = 0.f; pacc[mt][2] = 0.f; }
#pragma unroll
  for (int nt = 0; nt < 2; ++nt) {
    int nb = wid * 32 + nt * 16 + lhi * 4;
    float4v bv = *(const float4v*)(b1 + nb);
#pragma unroll
    for (int r = 0; r < 4; ++r) {
      float w20 = W2[(nb + r) * 3 + 0];
      float w21 = W2[(nb + r) * 3 + 1];
      float w22 = W2[(nb + r) * 3 + 2];
#pragma unroll
      for (int mt = 0; mt < 4; ++mt) {
        float h = silu_f(acc[nt][mt][r] + bv[r]);
        pacc[mt][0] += h * w20; pacc[mt][1] += h * w21; pacc[mt][2] += h * w22;
      }
    }
  }
  __syncthreads();  // all h1 reads done before Pp overlays Hc
#pragma unroll
  for (int mt = 0; mt < 4; ++mt)
#pragma unroll
    for (int o = 0; o < 3; ++o) {
      float v = pacc[mt][o];
      v += __shfl_xor(v, 16);
      v += __shfl_xor(v, 32);
      if (lane < 16) Pp[wid * 192 + (mt * 16 + llo) * 3 + o] = v;
    }
  __syncthreads();
  if (tid < 192) {
    int m = tid / 3, o = tid - m * 3;
    float v = b2[o];
#pragma unroll
    for (int ww = 0; ww < 16; ++ww) v += Pp[ww * 192 + m * 3 + o];
    pred[(size_t)(m0 + m) * 3 + o] = v;
  }
}

// ---------------------------------------------------------------------------
// Per-graph finalize: mean removal + analytic torque removal. 1 block/graph.
// ---------------------------------------------------------------------------
template<int NV>
__device__ __forceinline__ void block_reduce(const float* v, float (*sc)[16], int wid, int lane,
                                             float* tot) {
#pragma unroll
  for (int j = 0; j < NV; ++j) {
    float x = v[j];
#pragma unroll
    for (int off = 32; off >= 1; off >>= 1) x += __shfl_down(x, off);
    if (lane == 0) sc[wid][j] = x;
  }
  __syncthreads();
#pragma unroll
  for (int j = 0; j < NV; ++j) tot[j] = sc[0][j] + sc[1][j] + sc[2][j] + sc[3][j];
  __syncthreads();
}

__global__ __launch_bounds__(256) void finalize_kernel(
    const float* __restrict__ pred, const float* __restrict__ pos,
    const float* __restrict__ cell, const int* __restrict__ n_node,
    float* __restrict__ out) {
  __shared__ float sc[4][16];
  int g = blockIdx.x, tid = threadIdx.x;
  int wid = tid >> 6, lane = tid & 63;
  size_t i = (size_t)g * NPG + tid;

  float p0 = pred[i * 3 + 0], p1 = pred[i * 3 + 1], p2 = pred[i * 3 + 2];
  float q0 = pos[i * 3 + 0], q1 = pos[i * 3 + 1], q2 = pos[i * 3 + 2];

  float v1[6] = {p0, p1, p2, q0, q1, q2};
  float t1[6];
  block_reduce<6>(v1, sc, wid, lane, t1);

  float cnt = (float)n_node[g];
  float pc0 = p0 - t1[0] / cnt, pc1 = p1 - t1[1] / cnt, pc2 = p2 - t1[2] / cnt;
  float r0 = q0 - t1[3] / cnt, r1 = q1 - t1[4] / cnt, r2 = q2 - t1[5] / cnt;

  float v2[10] = {r1 * pc2 - r2 * pc1, r2 * pc0 - r0 * pc2, r0 * pc1 - r1 * pc0,
                  r0 * r0 + r1 * r1 + r2 * r2,
                  r0 * r0, r0 * r1, r0 * r2, r1 * r1, r1 * r2, r2 * r2};
  float t2[10];
  block_reduce<10>(v2, sc, wid, lane, t2);

  double s = (double)t2[3];
  double a = (double)t2[4] - s, b = (double)t2[5], c = (double)t2[6];
  double d = (double)t2[7] - s, e = (double)t2[8], f = (double)t2[9] - s;
  double A00 = d * f - e * e;
  double A01 = c * e - b * f;
  double A02 = b * e - c * d;
  double A11 = a * f - c * c;
  double A12 = b * c - a * e;
  double A22 = a * d - b * b;
  double det = a * A00 + b * A01 + c * A02;
  double rinv = 1.0 / det;
  double rhs0 = -(double)t2[0], rhs1 = -(double)t2[1], rhs2 = -(double)t2[2];
  double mu0 = (A00 * rhs0 + A01 * rhs1 + A02 * rhs2) * rinv;
  double mu1 = (A01 * rhs0 + A11 * rhs1 + A12 * rhs2) * rinv;
  double mu2 = (A02 * rhs0 + A12 * rhs1 + A22 * rhs2) * rinv;

  bool nopbc = true;
#pragma unroll
  for (int j = 0; j < 9; ++j) nopbc = nopbc && (cell[g * 9 + j] == 0.0f);

  float d0 = (float)((double)r1 * mu2 - (double)r2 * mu1);
  float d1 = (float)((double)r2 * mu0 - (double)r0 * mu2);
  float d2 = (float)((double)r0 * mu1 - (double)r1 * mu0);

  out[i * 3 + 0] = pc0 + (nopbc ? d0 : 0.0f);
  out[i * 3 + 1] = pc1 + (nopbc ? d1 : 0.0f);
  out[i * 3 + 2] = pc2 + (nopbc ? d2 : 0.0f);
}

// ---------------------------------------------------------------------------
extern "C" void kernel_launch(void* const* d_in, const int* in_sizes, int n_in,
                              void* d_out, int out_size, void* d_ws, size_t ws_size,
                              hipStream_t stream) {
  const float* feat = (const float*)d_in[0];
  const float* positions = (const float*)d_in[1];
  const float* cell = (const float*)d_in[2];
  const int* n_node = (const int*)d_in[3];
  const float* W0 = (const float*)d_in[4];
  const float* b0 = (const float*)d_in[5];
  const float* W1 = (const float*)d_in[6];
  const float* b1 = (const float*)d_in[7];
  const float* W2 = (const float*)d_in[8];
  const float* b2 = (const float*)d_in[9];
  float* out = (float*)d_out;

  char* ws = (char*)d_ws;
  ushort_t* W0pre = (ushort_t*)ws;                       // 256 KB (8 steps)
  ushort_t* W1pre = (ushort_t*)(ws + 262144);            // 512 KB (16 steps, contiguous)
  float* pred = (float*)(ws + 786432);                   // 3 MB

  hipLaunchKernelGGL(prep_weights, dim3(192), dim3(256), 0, stream, W0, W1, W0pre, W1pre);
  hipLaunchKernelGGL(fused_mlp, dim3(N_NODES / BM), dim3(1024), 0, stream,
                     feat, W0pre, W1pre, b0, b1, W2, b2, pred);
  hipLaunchKernelGGL(finalize_kernel, dim3(BGRAPHS), dim3(256), 0, stream, pred, positions, cell,
                     n_node, out);
}

// Round 14
// 270.449 us; speedup vs baseline: 2.5077x; 1.0376x over previous
//
#include <hip/hip_runtime.h>

#define N_NODES 262144
#define BGRAPHS 1024
#define NPG 256
#define LATENT 256
#define HIDDEN 512
#define BM 64

typedef unsigned short ushort_t;
typedef __attribute__((ext_vector_type(4))) float  f32x4;
typedef __attribute__((ext_vector_type(8))) short  short8;
typedef __attribute__((ext_vector_type(4))) int    int4v;
typedef __attribute__((ext_vector_type(2))) unsigned int uint2v;
typedef __attribute__((ext_vector_type(4))) float  float4v;

__device__ __forceinline__ unsigned int f2bf(float f) {
  union { float f; unsigned int u; } v; v.f = f;
  unsigned int u = v.u;
  return (u + 0x7fffu + ((u >> 16) & 1u)) >> 16;
}
__device__ __forceinline__ unsigned int cvtpk(float lo, float hi) {
  unsigned int r;
  asm("v_cvt_pk_bf16_f32 %0, %1, %2" : "=v"(r) : "v"(lo), "v"(hi));
  return r;
}
__device__ __forceinline__ float silu_f(float x) {
  return x * __builtin_amdgcn_rcpf(1.0f + __expf(-x));
}

// ---------------------------------------------------------------------------
// Weight prep: pre-tile W0/W1 (f32 [K][N]) into per-BK32-substep fragment
// images: byte(sub,p,n) = sub*32768 + p*8192 + n*16 (8 bf16: k=sub*32+p*8..+8,
// col n). W0pre (8 subs) + W1pre (16 subs) contiguous -> 24-sub stream.
// ---------------------------------------------------------------------------
__global__ void prep_weights(const float* __restrict__ W0, const float* __restrict__ W1,
                             ushort_t* __restrict__ W0pre, ushort_t* __restrict__ W1pre) {
  int c = blockIdx.x * 256 + threadIdx.x;   // 49152 cells of 8 elems
  const int C0 = 16384;
  const float* src;
  ushort_t* dst;
  int cc;
  if (c < C0) { src = W0; dst = W0pre; cc = c; }
  else        { src = W1; dst = W1pre; cc = c - C0; }
  int kstep = cc >> 11;
  int p = (cc >> 9) & 3;
  int n = cc & 511;
  int kb = kstep * 32 + p * 8;
  unsigned w[4];
#pragma unroll
  for (int j = 0; j < 4; ++j) {
    unsigned lo = f2bf(src[(size_t)(kb + 2 * j) * HIDDEN + n]);
    unsigned hi = f2bf(src[(size_t)(kb + 2 * j + 1) * HIDDEN + n]);
    w[j] = lo | (hi << 16);
  }
  *(int4v*)(dst + (size_t)cc * 8) = *(int4v*)w;
}

// ---------------------------------------------------------------------------
// Fused MLP. BM=64/block, N=512 full. 1024 threads = 16 waves, wave tile
// 64m x 32n (wc = wid). acc[2][4] = 32 AGPR. BK=64 steps (12 total),
// weights double-buffered in regs (wfA/wfB[4], prefetch issued before each
// MFMA cluster -> counted vmcnt, L2 latency hidden in-wave). 16-wave block
// forces 4 waves/SIMD -> unified cap 128, arch cap 96 [r8/r11/r12-verified].
// LDS: Hc 64 KB = h1 rows [64][1024B]; feat bf16 parked in high halves
// during GEMM1 (r9/r13-verified layout). Accumulation order identical to
// r13 (bit-exact numerics).
// ---------------------------------------------------------------------------
__global__ __launch_bounds__(1024, 1) void fused_mlp(
    const float* __restrict__ feat, const ushort_t* __restrict__ W0pre,
    const ushort_t* __restrict__ W1pre, const float* __restrict__ b0,
    const float* __restrict__ b1, const float* __restrict__ W2,
    const float* __restrict__ b2, float* __restrict__ pred) {
  __shared__ __align__(16) char Hc[65536];
  float* Pp = (float*)Hc;

  const int tid = threadIdx.x;
  const int wid = tid >> 6;    // n-slice: cols wid*32 .. wid*32+31
  const int lane = tid & 63;
  const int llo = lane & 15;
  const int lhi = lane >> 4;
  const int m0 = blockIdx.x * BM;

  // weight fragment base; BK32-sub s at +s*32768, frag nt (0..1) at +nt*256
  const char* wp = (const char*)W0pre + lhi * 8192 + (wid * 32 + llo) * 16;

#define WLOAD(DST, BASE)                               \
  DST[0] = *(const short8*)(BASE);                     \
  DST[1] = *(const short8*)((BASE) + 256);             \
  DST[2] = *(const short8*)((BASE) + 32768);           \
  DST[3] = *(const short8*)((BASE) + 32768 + 256);

  short8 wfA[4], wfB[4];
  WLOAD(wfA, wp)   // BK64 step 0 = subs 0,1

  // ---- park A: feat rows -> bf16 in Hc high halves (r9/r13 layout) ----
  {
    const int m = tid >> 4, q = tid & 15;
    const int cch = q >> 1, p0q = (q & 1) * 2;
    const float* ap = feat + (size_t)(m0 + m) * LATENT + cch * 32 + p0q * 8;
#pragma unroll
    for (int j = 0; j < 2; ++j) {
      const int p = p0q + j;
      float4v x = *(const float4v*)(ap + j * 8);
      float4v y = *(const float4v*)(ap + j * 8 + 4);
      unsigned u[4];
      u[0] = cvtpk(x[0], x[1]);
      u[1] = cvtpk(x[2], x[3]);
      u[2] = cvtpk(y[0], y[1]);
      u[3] = cvtpk(y[2], y[3]);
      int row = cch * 8 + p * 2 + (m >> 5);
      int slot = (m & 31) ^ (cch << 2) ^ (p << 1);
      *(int4v*)(Hc + row * 1024 + 512 + slot * 16) = *(int4v*)u;
    }
  }
  __syncthreads();

  f32x4 acc[2][4];
#pragma unroll
  for (int nt = 0; nt < 2; ++nt)
#pragma unroll
    for (int mt = 0; mt < 4; ++mt) acc[nt][mt] = 0.0f;

  const int pre = llo ^ (lhi << 1);   // no bit 4

  // one BK32 sub-step of GEMM1: subs SS with wf frags WF[I0],WF[I1]
#define G1SUB(WF, I0, I1, SS)                                                            \
  {                                                                                      \
    const char* abase = Hc + 512 + (SS) * 8192 + lhi * 2048;                             \
    const int off_e = (pre ^ ((SS) << 2)) << 4;                                          \
    _Pragma("unroll") for (int mt = 0; mt < 4; ++mt) {                                   \
      short8 xf = *(const short8*)(abase + ((mt >> 1) << 10) +                           \
                                   ((mt & 1) ? (off_e ^ 256) : off_e));                  \
      acc[0][mt] = __builtin_amdgcn_mfma_f32_16x16x32_bf16(WF[I0], xf, acc[0][mt], 0, 0, 0); \
      acc[1][mt] = __builtin_amdgcn_mfma_f32_16x16x32_bf16(WF[I1], xf, acc[1][mt], 0, 0, 0); \
    }                                                                                    \
  }

  // ================= GEMM1: 4 BK64 steps (subs 0..7) =================
#pragma unroll 1
  for (int S = 0; S < 2; ++S) {
    WLOAD(wfB, wp + (4 * S + 2) * 32768)   // prefetch odd step
    __builtin_amdgcn_s_setprio(1);
    G1SUB(wfA, 0, 1, 4 * S + 0)
    G1SUB(wfA, 2, 3, 4 * S + 1)
    __builtin_amdgcn_s_setprio(0);
    WLOAD(wfA, wp + (4 * S + 4) * 32768)   // prefetch next even (S=1: GEMM2 step0)
    __builtin_amdgcn_s_setprio(1);
    G1SUB(wfB, 0, 1, 4 * S + 2)
    G1SUB(wfB, 2, 3, 4 * S + 3)
    __builtin_amdgcn_s_setprio(0);
  }

  // ---- epilogue 1: h1 = silu(acc + b0) -> Hc rows (swizzled) ----
  __syncthreads();  // all park reads done
#pragma unroll
  for (int nt = 0; nt < 2; ++nt) {
    int nb = wid * 32 + nt * 16 + lhi * 4;
    float4v bv = *(const float4v*)(b0 + nb);
#pragma unroll
    for (int mt = 0; mt < 4; ++mt) {
      int m = mt * 16 + llo;
      float s0 = silu_f(acc[nt][mt][0] + bv[0]);
      float s1 = silu_f(acc[nt][mt][1] + bv[1]);
      float s2 = silu_f(acc[nt][mt][2] + bv[2]);
      float s3 = silu_f(acc[nt][mt][3] + bv[3]);
      uint2v pk;
      pk.x = cvtpk(s0, s1);
      pk.y = cvtpk(s2, s3);
      *(uint2v*)(Hc + m * 1024 + ((nb * 2) ^ (llo << 4))) = pk;
    }
  }
#pragma unroll
  for (int nt = 0; nt < 2; ++nt)
#pragma unroll
    for (int mt = 0; mt < 4; ++mt) acc[nt][mt] = 0.0f;
  __syncthreads();  // h1 visible to all waves

  // one BK32 sub-step of GEMM2: sub TT (0..15)
#define G2SUB(WF, I0, I1, TT)                                                            \
  {                                                                                      \
    const int col = (((TT) * 64 + lhi * 16) ^ (llo << 4));                               \
    _Pragma("unroll") for (int mt = 0; mt < 4; ++mt) {                                   \
      short8 xf = *(const short8*)(hrow + mt * 16384 + col);                             \
      acc[0][mt] = __builtin_amdgcn_mfma_f32_16x16x32_bf16(WF[I0], xf, acc[0][mt], 0, 0, 0); \
      acc[1][mt] = __builtin_amdgcn_mfma_f32_16x16x32_bf16(WF[I1], xf, acc[1][mt], 0, 0, 0); \
    }                                                                                    \
  }

  // ================= GEMM2: 8 BK64 steps (subs 0..15) =================
  {
    const char* hrow = Hc + llo * 1024;
    const char* wg = wp + 8 * 32768;   // wfA already holds subs 0,1
#pragma unroll 1
    for (int T = 0; T < 4; ++T) {
      WLOAD(wfB, wg + (4 * T + 2) * 32768)
      __builtin_amdgcn_s_setprio(1);
      G2SUB(wfA, 0, 1, 4 * T + 0)
      G2SUB(wfA, 2, 3, 4 * T + 1)
      __builtin_amdgcn_s_setprio(0);
      {
        const char* nx = (T < 3) ? wg + (4 * T + 4) * 32768 : wg;  // dummy at end
        WLOAD(wfA, nx)
      }
      __builtin_amdgcn_s_setprio(1);
      G2SUB(wfB, 0, 1, 4 * T + 2)
      G2SUB(wfB, 2, 3, 4 * T + 3)
      __builtin_amdgcn_s_setprio(0);
    }
  }

  // ---- epilogue 2: pacc = silu(acc + b1) @ W2 (registers only) ----
  float pacc[4][3];
#pragma unroll
  for (int mt = 0; mt < 4; ++mt) { pacc[mt][0] = 0.f; pacc[mt][1] = 0.f; pacc[mt][2] = 0.f; }
#pragma unroll
  for (int nt = 0; nt < 2; ++nt) {
    int nb = wid * 32 + nt * 16 + lhi * 4;
    float4v bv = *(const float4v*)(b1 + nb);
#pragma unroll
    for (int r = 0; r < 4; ++r) {
      float w20 = W2[(nb + r) * 3 + 0];
      float w21 = W2[(nb + r) * 3 + 1];
      float w22 = W2[(nb + r) * 3 + 2];
#pragma unroll
      for (int mt = 0; mt < 4; ++mt) {
        float h = silu_f(acc[nt][mt][r] + bv[r]);
        pacc[mt][0] += h * w20; pacc[mt][1] += h * w21; pacc[mt][2] += h * w22;
      }
    }
  }
  __syncthreads();  // all h1 reads done before Pp overlays Hc
#pragma unroll
  for (int mt = 0; mt < 4; ++mt)
#pragma unroll
    for (int o = 0; o < 3; ++o) {
      float v = pacc[mt][o];
      v += __shfl_xor(v, 16);
      v += __shfl_xor(v, 32);
      if (lane < 16) Pp[wid * 192 + (mt * 16 + llo) * 3 + o] = v;
    }
  __syncthreads();
  if (tid < 192) {
    int m = tid / 3, o = tid - m * 3;
    float v = b2[o];
#pragma unroll
    for (int ww = 0; ww < 16; ++ww) v += Pp[ww * 192 + m * 3 + o];
    pred[(size_t)(m0 + m) * 3 + o] = v;
  }
}

// ---------------------------------------------------------------------------
// Per-graph finalize: mean removal + analytic torque removal. 1 block/graph.
// ---------------------------------------------------------------------------
template<int NV>
__device__ __forceinline__ void block_reduce(const float* v, float (*sc)[16], int wid, int lane,
                                             float* tot) {
#pragma unroll
  for (int j = 0; j < NV; ++j) {
    float x = v[j];
#pragma unroll
    for (int off = 32; off >= 1; off >>= 1) x += __shfl_down(x, off);
    if (lane == 0) sc[wid][j] = x;
  }
  __syncthreads();
#pragma unroll
  for (int j = 0; j < NV; ++j) tot[j] = sc[0][j] + sc[1][j] + sc[2][j] + sc[3][j];
  __syncthreads();
}

__global__ __launch_bounds__(256) void finalize_kernel(
    const float* __restrict__ pred, const float* __restrict__ pos,
    const float* __restrict__ cell, const int* __restrict__ n_node,
    float* __restrict__ out) {
  __shared__ float sc[4][16];
  int g = blockIdx.x, tid = threadIdx.x;
  int wid = tid >> 6, lane = tid & 63;
  size_t i = (size_t)g * NPG + tid;

  float p0 = pred[i * 3 + 0], p1 = pred[i * 3 + 1], p2 = pred[i * 3 + 2];
  float q0 = pos[i * 3 + 0], q1 = pos[i * 3 + 1], q2 = pos[i * 3 + 2];

  float v1[6] = {p0, p1, p2, q0, q1, q2};
  float t1[6];
  block_reduce<6>(v1, sc, wid, lane, t1);

  float cnt = (float)n_node[g];
  float pc0 = p0 - t1[0] / cnt, pc1 = p1 - t1[1] / cnt, pc2 = p2 - t1[2] / cnt;
  float r0 = q0 - t1[3] / cnt, r1 = q1 - t1[4] / cnt, r2 = q2 - t1[5] / cnt;

  float v2[10] = {r1 * pc2 - r2 * pc1, r2 * pc0 - r0 * pc2, r0 * pc1 - r1 * pc0,
                  r0 * r0 + r1 * r1 + r2 * r2,
                  r0 * r0, r0 * r1, r0 * r2, r1 * r1, r1 * r2, r2 * r2};
  float t2[10];
  block_reduce<10>(v2, sc, wid, lane, t2);

  double s = (double)t2[3];
  double a = (double)t2[4] - s, b = (double)t2[5], c = (double)t2[6];
  double d = (double)t2[7] - s, e = (double)t2[8], f = (double)t2[9] - s;
  double A00 = d * f - e * e;
  double A01 = c * e - b * f;
  double A02 = b * e - c * d;
  double A11 = a * f - c * c;
  double A12 = b * c - a * e;
  double A22 = a * d - b * b;
  double det = a * A00 + b * A01 + c * A02;
  double rinv = 1.0 / det;
  double rhs0 = -(double)t2[0], rhs1 = -(double)t2[1], rhs2 = -(double)t2[2];
  double mu0 = (A00 * rhs0 + A01 * rhs1 + A02 * rhs2) * rinv;
  double mu1 = (A01 * rhs0 + A11 * rhs1 + A12 * rhs2) * rinv;
  double mu2 = (A02 * rhs0 + A12 * rhs1 + A22 * rhs2) * rinv;

  bool nopbc = true;
#pragma unroll
  for (int j = 0; j < 9; ++j) nopbc = nopbc && (cell[g * 9 + j] == 0.0f);

  float d0 = (float)((double)r1 * mu2 - (double)r2 * mu1);
  float d1 = (float)((double)r2 * mu0 - (double)r0 * mu2);
  float d2 = (float)((double)r0 * mu1 - (double)r1 * mu0);

  out[i * 3 + 0] = pc0 + (nopbc ? d0 : 0.0f);
  out[i * 3 + 1] = pc1 + (nopbc ? d1 : 0.0f);
  out[i * 3 + 2] = pc2 + (nopbc ? d2 : 0.0f);
}

// ---------------------------------------------------------------------------
extern "C" void kernel_launch(void* const* d_in, const int* in_sizes, int n_in,
                              void* d_out, int out_size, void* d_ws, size_t ws_size,
                              hipStream_t stream) {
  const float* feat = (const float*)d_in[0];
  const float* positions = (const float*)d_in[1];
  const float* cell = (const float*)d_in[2];
  const int* n_node = (const int*)d_in[3];
  const float* W0 = (const float*)d_in[4];
  const float* b0 = (const float*)d_in[5];
  const float* W1 = (const float*)d_in[6];
  const float* b1 = (const float*)d_in[7];
  const float* W2 = (const float*)d_in[8];
  const float* b2 = (const float*)d_in[9];
  float* out = (float*)d_out;

  char* ws = (char*)d_ws;
  ushort_t* W0pre = (ushort_t*)ws;                       // 256 KB (8 subs)
  ushort_t* W1pre = (ushort_t*)(ws + 262144);            // 512 KB (16 subs, contiguous)
  float* pred = (float*)(ws + 786432);                   // 3 MB

  hipLaunchKernelGGL(prep_weights, dim3(192), dim3(256), 0, stream, W0, W1, W0pre, W1pre);
  hipLaunchKernelGGL(fused_mlp, dim3(N_NODES / BM), dim3(1024), 0, stream,
                     feat, W0pre, W1pre, b0, b1, W2, b2, pred);
  hipLaunchKernelGGL(finalize_kernel, dim3(BGRAPHS), dim3(256), 0, stream, pred, positions, cell,
                     n_node, out);
}